// Round 8
// baseline (337.529 us; speedup 1.0000x reference)
//
#include <hip/hip_runtime.h>

// Problem constants
#define BB    4
#define LL    4096
#define DM    1024
#define HH    16
#define SEGC  64
#define HDC   64
#define NSEGC 64
#define NEGV  -1.0e10f

typedef __bf16 bf16x8 __attribute__((ext_vector_type(8)));
typedef float  f32x4  __attribute__((ext_vector_type(4)));

__device__ __forceinline__ float bf2f(unsigned short s) {
  union { unsigned int u; float f; } x; x.u = ((unsigned int)s) << 16; return x.f;
}
__device__ __forceinline__ unsigned short f2bf(float f) {
  union { float f; unsigned int u; } x; x.f = f;
  unsigned int u = x.u;
  return (unsigned short)((u + 0x7fffu + ((u >> 16) & 1u)) >> 16);
}

// async global->LDS, 16 bytes per lane; LDS dest is wave-uniform base,
// lane i lands at l + i*16 bytes.
__device__ __forceinline__ void gl2lds16(const unsigned short* g, unsigned short* l) {
  __builtin_amdgcn_global_load_lds(
      (const __attribute__((address_space(1))) unsigned int*)g,
      (__attribute__((address_space(3))) unsigned int*)l,
      16, 0, 0);
}

// copy 16 bf16 from global (16B-aligned) to LDS (4B-aligned) via VGPR
__device__ __forceinline__ void g2lds16(unsigned short* dst, const unsigned short* src) {
  int4 a = *(const int4*)(src);
  int4 b = *(const int4*)(src + 8);
  unsigned int* d = (unsigned int*)dst;
  const unsigned int* pa = (const unsigned int*)&a;
  const unsigned int* pb = (const unsigned int*)&b;
  d[0]=pa[0]; d[1]=pa[1]; d[2]=pa[2]; d[3]=pa[3];
  d[4]=pb[0]; d[5]=pb[1]; d[6]=pb[2]; d[7]=pb[3];
}

// ---------------------------------------------------------------------------
// cvt_x: f32 -> bf16, 8 elems/thread
// ---------------------------------------------------------------------------
__global__ __launch_bounds__(256) void cvt_x(const float* __restrict__ x,
                                             unsigned short* __restrict__ xb) {
  const size_t i = ((size_t)blockIdx.x * 256 + threadIdx.x) * 8;
  float4 a = *(const float4*)(x + i);
  float4 b = *(const float4*)(x + i + 4);
  unsigned short o[8];
  o[0]=f2bf(a.x); o[1]=f2bf(a.y); o[2]=f2bf(a.z); o[3]=f2bf(a.w);
  o[4]=f2bf(b.x); o[5]=f2bf(b.y); o[6]=f2bf(b.z); o[7]=f2bf(b.w);
  *(int4*)(xb + i) = *(const int4*)o;
}

// ---------------------------------------------------------------------------
// transpose_w: LDS tile-transpose f32[1024][1024] -> bf16 [N][K].
// ---------------------------------------------------------------------------
__global__ __launch_bounds__(256) void transpose_w(
    const float* __restrict__ wq, const float* __restrict__ wk,
    const float* __restrict__ wv, const float* __restrict__ wo,
    unsigned short* __restrict__ WqkvT, unsigned short* __restrict__ woT) {
  __shared__ unsigned short TS[64 * 65];

  const int z  = blockIdx.z;
  const int bx = blockIdx.x;
  const int by = blockIdx.y;
  const int t  = threadIdx.x;

  const float* src; unsigned short* dst; float scale = 1.0f;
  if (z == 0)      { src = wq; dst = WqkvT;               scale = 0.125f; }
  else if (z == 1) { src = wk; dst = WqkvT + 1024 * 1024; }
  else if (z == 2) { src = wv; dst = WqkvT + 2048 * 1024; }
  else             { src = wo; dst = woT; }

  const int rr = t >> 4;
  const int c4 = (t & 15) * 4;
  #pragma unroll
  for (int it = 0; it < 4; it++) {
    const int r = it * 16 + rr;
    float4 f = *(const float4*)(src + (size_t)(by * 64 + r) * 1024 + bx * 64 + c4);
    TS[(c4 + 0) * 65 + r] = f2bf(f.x * scale);
    TS[(c4 + 1) * 65 + r] = f2bf(f.y * scale);
    TS[(c4 + 2) * 65 + r] = f2bf(f.z * scale);
    TS[(c4 + 3) * 65 + r] = f2bf(f.w * scale);
  }
  __syncthreads();

  const int wr = t >> 3;
  const int w8 = (t & 7) * 8;
  #pragma unroll
  for (int it = 0; it < 2; it++) {
    const int n = it * 32 + wr;
    unsigned short o[8];
    #pragma unroll
    for (int j = 0; j < 8; j++) o[j] = TS[n * 65 + w8 + j];
    *(int4*)(dst + (size_t)(bx * 64 + n) * 1024 + by * 64 + w8) = *(const int4*)o;
  }
}

// ---------------------------------------------------------------------------
// gemm128x256 (round-8): C[16384 x N] = A @ Bt^T (bf16, f32 acc)
//
// NEW GEOMETRY for 2-blocks/CU co-residency (m114/m97 mechanism): the 256^2
// kernel was 128KB LDS + ~248 regs/wave -> exactly 1 block/CU, so every
// barrier/vmcnt stalled the whole CU (MfmaUtil pinned ~42% across 3 schedule
// variants). Now: 128x256 tile, BK=32, 8 waves (wave tile 64x64), LDS 48KB,
// acc[4][4]=64 regs + 8 frags ~= 110 regs -> 4 waves/SIMD -> 2 blocks/CU.
// Partner block hides barrier stalls, prologue latency, and the ~5us C-write
// drain. Out-proj grid becomes 512 -> co-residency there too (was 1/CU).
//
// Per K-tile (32 total): 3 DMA stages/wave, 8 ds_read_b128, 16 MFMA.
// vmcnt ledger: enter iter with 3 outstanding (t+1); +3 (t+2) = 6; VMW(3)
// retires t+1; VMW before BAR => after BAR all waves' t+1 loads landed.
// WAR: reads -> lgkmcnt(0) -> BAR -> re-stage same buffer.
// Subtile swizzle identical to verified 256^2 kernel (involution checked).
// XCD band mapping: xcd=wg&7, lm=(wg>>3)&15, nt=wg>>7(ish): A band 4MB/XCD
// L2-resident, B phase 512KB. Bijective for nwg=1536 and 512.
// ---------------------------------------------------------------------------
template <bool C_F32>
__global__ __launch_bounds__(512, 4) void gemm128x256(
    const unsigned short* __restrict__ A,
    const unsigned short* __restrict__ Bt,
    void* __restrict__ Cv,
    int ldc)
{
  // A: 8 subtiles (16r x 32k) per buf; B: 16 subtiles per buf. 48KB total.
  __shared__ __align__(16) unsigned short LA[2][8][512];
  __shared__ __align__(16) unsigned short LB[2][16][512];

  const int t    = threadIdx.x;
  const int wave = t >> 6;
  const int lane = t & 63;
  const int l15  = lane & 15;
  const int q4   = lane >> 4;
  const int wm   = wave >> 2;        // 0..1 : 64-row band
  const int wn   = wave & 3;         // 0..3 : 64-col band

  // XCD-band mapping: 128 m-tiles total, 16 per XCD (4MB A window).
  const int wg  = blockIdx.x;
  const int xcd = wg & 7;
  const int r_  = wg >> 3;
  const int lm  = r_ & 15;
  const int nt  = r_ >> 4;
  const int m0  = ((xcd << 4) + lm) << 7;   // *128
  const int n0  = nt << 8;                  // *256

  // staging geometry: wave stages one 16x32 subtile per call.
  // lane: row-in-subtile = lane>>2, col = (lane&3)*8 ^ swz(rowbit3)
  const int srow = lane >> 2;
  const int scol = ((lane & 3) << 3) ^ (((lane >> 5) & 1) << 4);
  const unsigned short* Abase = A  + (size_t)(m0 + wave * 16 + srow) * 1024 + scol;
  const unsigned short* Bbase = Bt + (size_t)(n0 + wave * 16 + srow) * 1024 + scol;

  // swizzled ds_read offset (u16 units) within a subtile
  const int rdoff = l15 * 32 + ((q4 * 8) ^ (((l15 >> 3) & 1) << 4));

#define SA_(d, kt)  gl2lds16(Abase + (size_t)(kt) * 32, &LA[d][wave][0])
#define SB0_(d, kt) gl2lds16(Bbase + (size_t)(kt) * 32, &LB[d][wave][0])
#define SB1_(d, kt) gl2lds16(Bbase + (size_t)128 * 1024 + (size_t)(kt) * 32, \
                             &LB[d][8 + wave][0])
#define LDA8(d, i) (*(const bf16x8*)(&LA[d][wm * 4 + (i)][0] + rdoff))
#define LDB8(d, j) (*(const bf16x8*)(&LB[d][wn * 4 + (j)][0] + rdoff))
#define BAR()   asm volatile("s_barrier" ::: "memory")
#define LGKM0() asm volatile("s_waitcnt lgkmcnt(0)" ::: "memory")
#define VMW(n)  asm volatile("s_waitcnt vmcnt(" #n ")" ::: "memory")
#define MFMA_(av, bv, cv) __builtin_amdgcn_mfma_f32_16x16x32_bf16(av, bv, cv, 0, 0, 0)

  f32x4 acc[4][4];
  #pragma unroll
  for (int i = 0; i < 4; ++i)
    #pragma unroll
    for (int j = 0; j < 4; ++j) acc[i][j] = (f32x4){0.f, 0.f, 0.f, 0.f};

  // Prologue: stage t0 -> buf0, t1 -> buf1 (3 loads each). VMW(3): t0 landed.
  SA_(0, 0); SB0_(0, 0); SB1_(0, 0);
  SA_(1, 1); SB0_(1, 1); SB1_(1, 1);
  VMW(3); BAR();

  #pragma unroll 1
  for (int it = 0; it < 32; ++it) {
    const int cur = it & 1;
    const int nxt = (it + 2) & 31;   // wraps harmlessly on last 2 iterations

    bf16x8 a[4], b[4];
    #pragma unroll
    for (int i = 0; i < 4; ++i) a[i] = LDA8(cur, i);
    #pragma unroll
    for (int j = 0; j < 4; ++j) b[j] = LDB8(cur, j);
    LGKM0();           // my reads retired (frags in regs)
    BAR();             // all waves' reads retired -> safe to overwrite buf[cur]
    SA_(cur, nxt); SB0_(cur, nxt); SB1_(cur, nxt);

    __builtin_amdgcn_s_setprio(1);
    #pragma unroll
    for (int i = 0; i < 4; ++i)
      #pragma unroll
      for (int j = 0; j < 4; ++j)
        acc[i][j] = MFMA_(a[i], b[j], acc[i][j]);
    __builtin_amdgcn_s_setprio(0);

    VMW(3);            // t+1's 3 loads landed (per wave), then...
    BAR();             // ...all waves' t+1 loads landed -> next iter may read
  }

  // Epilogue: wave owns 64x64 at (wm*64, wn*64)
  #pragma unroll
  for (int i = 0; i < 4; ++i) {
    #pragma unroll
    for (int j = 0; j < 4; ++j) {
      const int col = n0 + wn * 64 + j * 16 + l15;
      #pragma unroll
      for (int r = 0; r < 4; ++r) {
        const int row = m0 + wm * 64 + i * 16 + q4 * 4 + r;
        if (C_F32) ((float*)Cv)[(size_t)row * ldc + col] = acc[i][j][r];
        else ((unsigned short*)Cv)[(size_t)row * ldc + col] = f2bf(acc[i][j][r]);
      }
    }
  }
  VMW(0);  // drain straggler LDS-DMA before endpgm (LDS gets reused)

#undef SA_
#undef SB0_
#undef SB1_
#undef LDA8
#undef LDB8
#undef BAR
#undef LGKM0
#undef VMW
#undef MFMA_
}

// ---------------------------------------------------------------------------
// Span kernel (v2, known-good): per (chunk c, head h), 1 wave.
// Dual-accumulator + unroll to pipeline LDS-read latency in the 64-loops.
// ---------------------------------------------------------------------------
__global__ __launch_bounds__(64) void span_kernel(
    const unsigned short* __restrict__ qkv,
    unsigned short* __restrict__ spanK,   // [256][16][64]
    unsigned short* __restrict__ spanV)   // [256][16][64]
{
  __shared__ unsigned short QS[64 * 66], KS[64 * 66], VS[64 * 66];
  __shared__ float mqs[64], ws[64];

  const int c = blockIdx.x;
  const int h = blockIdx.y;
  const int b = c >> 6, n = c & 63;
  const int t = threadIdx.x;

  const size_t rowbase = ((size_t)(b * LL + n * SEGC + t)) * 3072 + h * 64;
  #pragma unroll
  for (int j = 0; j < 4; j++) {
    g2lds16(QS + t * 66 + j * 16, qkv + rowbase + j * 16);
    g2lds16(KS + t * 66 + j * 16, qkv + rowbase + 1024 + j * 16);
    g2lds16(VS + t * 66 + j * 16, qkv + rowbase + 2048 + j * 16);
  }
  __syncthreads();

  float mqa = -3.0e38f, mqb = -3.0e38f, ska = -3.0e38f, skc = -3.0e38f;
  #pragma unroll 8
  for (int r = 0; r < 64; r += 2) {
    mqa = fmaxf(mqa, bf2f(QS[r * 66 + t]));
    mqb = fmaxf(mqb, bf2f(QS[(r + 1) * 66 + t]));
    ska = fmaxf(ska, bf2f(KS[r * 66 + t]));
    skc = fmaxf(skc, bf2f(KS[(r + 1) * 66 + t]));
  }
  mqs[t] = fmaxf(mqa, mqb);
  spanK[((size_t)c * 16 + h) * 64 + t] = f2bf(fmaxf(ska, skc));
  __syncthreads();

  float l0 = 0.f, l1 = 0.f;
  #pragma unroll 8
  for (int d = 0; d < 64; d += 2) {
    l0 += mqs[d] * bf2f(KS[t * 66 + d]);
    l1 += mqs[d + 1] * bf2f(KS[t * 66 + d + 1]);
  }
  float logit = l0 + l1;
  float m = logit;
  #pragma unroll
  for (int off = 32; off; off >>= 1) m = fmaxf(m, __shfl_xor(m, off, 64));
  float e = __expf(logit - m);
  float s = e;
  #pragma unroll
  for (int off = 32; off; off >>= 1) s += __shfl_xor(s, off, 64);
  ws[t] = e / s;
  __syncthreads();

  float sv0 = 0.f, sv1 = 0.f;
  #pragma unroll 8
  for (int kk = 0; kk < 64; kk += 2) {
    sv0 += ws[kk] * bf2f(VS[kk * 66 + t]);
    sv1 += ws[kk + 1] * bf2f(VS[(kk + 1) * 66 + t]);
  }
  spanV[((size_t)c * 16 + h) * 64 + t] = f2bf(sv0 + sv1);
}

// ---------------------------------------------------------------------------
// Joint attention kernel (MFMA): per (chunk c, head h), 4 waves.
// v3: K-joint staged into LDS KJ[128][72] via coalesced g2lds16; VT staging
// keeps the v2 XOR swizzle (element-verified).
// ---------------------------------------------------------------------------
__global__ __launch_bounds__(256) void attn_kernel(
    const unsigned short* __restrict__ qkv,
    const unsigned short* __restrict__ spanK,
    const unsigned short* __restrict__ spanV,
    unsigned short* __restrict__ att)
{
  __shared__ __align__(16) unsigned short KJ[128 * 72];  // [r][72]: r<64 local K, r>=64 spanK
  __shared__ __align__(16) unsigned short VT[64 * 136];  // [f][k'-swizzled]
  __shared__ __align__(16) unsigned short WL[64 * 136];  // [att row][k'] weights

  const int c = blockIdx.x;
  const int h = blockIdx.y;
  const int b = c >> 6, n = c & 63;
  const int t = threadIdx.x;
  const int wave = t >> 6;
  const int lane = t & 63;
  const int l15  = lane & 15;
  const int q4   = lane >> 4;

  // ---- stage K-joint into KJ (coalesced: 4 threads x 32B = 128B per row)
  {
    const int r  = t >> 2;            // 0..63
    const int qq = (t & 3) * 16;      // 0,16,32,48 (u16)
    g2lds16(KJ + r * 72 + qq,
            qkv + ((size_t)(b * LL + n * SEGC + r)) * 3072 + 1024 + h * 64 + qq);
    g2lds16(KJ + (64 + r) * 72 + qq,
            spanK + ((size_t)(b * 64 + r) * 16 + h) * 64 + qq);
  }

  // ---- stage V' transposed into VT (v2 swizzle)
  #pragma unroll
  for (int it = 0; it < 4; it++) {
    const int idx = t + 256 * it;
    const int kp  = idx >> 3;           // joint key 0..127
    const int fc  = (idx & 7) * 8;
    const unsigned short* src;
    if (kp < 64)
      src = qkv + ((size_t)(b * LL + n * SEGC + kp)) * 3072 + 2048 + h * 64 + fc;
    else
      src = spanV + ((size_t)(b * 64 + (kp - 64)) * 16 + h) * 64 + fc;
    int4 val = *(const int4*)src;
    const unsigned short* e = (const unsigned short*)&val;
    const int kb = kp >> 3;             // k'-block 0..15
    #pragma unroll
    for (int i = 0; i < 8; i++) {
      const int f  = fc + i;
      const int nb = (kb & 8) | ((kb ^ (f >> 3)) & 7);   // swizzled block
      VT[f * 136 + nb * 8 + (kp & 7)] = e[i];
    }
  }

  // Q fragments: direct global (read once, no reuse)
  bf16x8 af[2];
  {
    const size_t qbase = ((size_t)(b * LL + n * SEGC + wave * 16 + l15)) * 3072
                         + h * 64 + q4 * 8;
    af[0] = *(const bf16x8*)(qkv + qbase);
    af[1] = *(const bf16x8*)(qkv + qbase + 32);
  }

  __syncthreads();   // KJ + VT complete

  f32x4 accl[8];
  #pragma unroll
  for (int tt = 0; tt < 8; tt++) accl[tt] = (f32x4){0.f, 0.f, 0.f, 0.f};

  #pragma unroll
  for (int s = 0; s < 2; s++) {
    bf16x8 bfr[8];
    #pragma unroll
    for (int tt = 0; tt < 8; tt++)
      bfr[tt] = *(const bf16x8*)(KJ + (tt * 16 + l15) * 72 + s * 32 + q4 * 8);
    #pragma unroll
    for (int tt = 0; tt < 8; tt++)
      accl[tt] = __builtin_amdgcn_mfma_f32_16x16x32_bf16(af[s], bfr[tt], accl[tt], 0, 0, 0);
  }

  #pragma unroll
  for (int tt = 0; tt < 8; tt++) {
    const int col = (tt & 3) * 16 + l15;
    #pragma unroll
    for (int rr = 0; rr < 4; rr++) {
      const int r_att = wave * 16 + q4 * 4 + rr;
      const bool valid = (tt < 4) ? (col <= r_att) : (col < n);
      if (!valid) accl[tt][rr] = NEGV;
    }
  }

  #pragma unroll
  for (int rr = 0; rr < 4; rr++) {
    float mx = accl[0][rr];
    #pragma unroll
    for (int tt = 1; tt < 8; tt++) mx = fmaxf(mx, accl[tt][rr]);
    #pragma unroll
    for (int msk = 1; msk < 16; msk <<= 1) mx = fmaxf(mx, __shfl_xor(mx, msk, 64));
    float sm = 0.f;
    float ex[8];
    #pragma unroll
    for (int tt = 0; tt < 8; tt++) { ex[tt] = __expf(accl[tt][rr] - mx); sm += ex[tt]; }
    #pragma unroll
    for (int msk = 1; msk < 16; msk <<= 1) sm += __shfl_xor(sm, msk, 64);
    const float inv = 1.0f / sm;
    const int r_att = wave * 16 + q4 * 4 + rr;
    #pragma unroll
    for (int tt = 0; tt < 8; tt++) {
      const int colj = (tt < 4) ? (tt * 16 + l15) : (64 + (tt - 4) * 16 + l15);
      WL[r_att * 136 + colj] = f2bf(ex[tt] * inv);
    }
  }

  __syncthreads();

  f32x4 accm[4];
  #pragma unroll
  for (int j = 0; j < 4; j++) accm[j] = (f32x4){0.f, 0.f, 0.f, 0.f};
  #pragma unroll
  for (int s = 0; s < 4; s++) {
    const bf16x8 aw = *(const bf16x8*)(WL + (wave * 16 + l15) * 136 + s * 32 + q4 * 8);
    #pragma unroll
    for (int j = 0; j < 4; j++) {
      const int f  = j * 16 + l15;
      const int kb = s * 4 + q4;                          // k'-block 0..15
      const int nb = (kb & 8) | ((kb ^ (f >> 3)) & 7);    // same swizzle as write
      const bf16x8 bv = *(const bf16x8*)(VT + f * 136 + nb * 8);
      accm[j] = __builtin_amdgcn_mfma_f32_16x16x32_bf16(aw, bv, accm[j], 0, 0, 0);
    }
  }

  #pragma unroll
  for (int j = 0; j < 4; j++) {
    #pragma unroll
    for (int rr = 0; rr < 4; rr++) {
      const int row = wave * 16 + q4 * 4 + rr;
      const int col = j * 16 + l15;
      att[((size_t)(b * LL + n * SEGC + row)) * 1024 + h * 64 + col] = f2bf(accm[j][rr]);
    }
  }
}

// ---------------------------------------------------------------------------
extern "C" void kernel_launch(void* const* d_in, const int* in_sizes, int n_in,
                              void* d_out, int out_size, void* d_ws, size_t ws_size,
                              hipStream_t stream) {
  const float* x  = (const float*)d_in[0];
  const float* wq = (const float*)d_in[1];
  const float* wk = (const float*)d_in[2];
  const float* wv = (const float*)d_in[3];
  const float* wo = (const float*)d_in[4];
  float* out = (float*)d_out;

  unsigned short* wsp   = (unsigned short*)d_ws;
  unsigned short* xb    = wsp;                       // 16,777,216 (aliased as attb later)
  unsigned short* qkv   = xb + 16777216;             // 50,331,648
  unsigned short* WqkvT = qkv + 50331648;            //  3,145,728
  unsigned short* woT   = WqkvT + 3145728;           //  1,048,576
  unsigned short* skb   = woT + 1048576;             //    262,144
  unsigned short* svb   = skb + 262144;              //    262,144
  unsigned short* attb  = xb;   // alias: xb dead after QKV GEMM

  cvt_x<<<8192, 256, 0, stream>>>(x, xb);
  transpose_w<<<dim3(16, 16, 4), 256, 0, stream>>>(wq, wk, wv, wo, WqkvT, woT);
  // QKV: M=16384/128 x N=3072/256 -> 128 x 12 = 1536 blocks (2/CU resident)
  gemm128x256<false><<<1536, 512, 0, stream>>>(xb, WqkvT, (void*)qkv, 3072);
  span_kernel<<<dim3(256, 16), 64, 0, stream>>>(qkv, skb, svb);
  attn_kernel<<<dim3(256, 16), 256, 0, stream>>>(qkv, skb, svb, attb);
  // out-proj: 128 x 4 = 512 blocks (2/CU resident)
  gemm128x256<true><<<512, 512, 0, stream>>>(attb, woT, (void*)out, 1024);
}